// Round 11
// baseline (262.942 us; speedup 1.0000x reference)
//
#include <hip/hip_runtime.h>
#include <math.h>
#include <float.h>

#define NFEAT 300
#define HID 32
#define NCLS 10
#define GP 16     // padded row stride for layer-2 logits
#define BSZ 128   // nodes per dst-bucket (bucket = dst >> 7)
#define TILE 8192 // edges per k_part tile

__global__ void k_zero_i(int* __restrict__ p, int n) {
    int i = blockIdx.x * 256 + threadIdx.x;
    if (i < n) p[i] = 0;
}

// bucket-level histogram: LDS-privatized, merged via global atomics (782 counters)
__global__ __launch_bounds__(256) void k_bhist(const int* __restrict__ ei, int E, int NB,
                                               int* __restrict__ bcnt) {
    __shared__ int h[1024];
    for (int i = threadIdx.x; i < NB; i += 256) h[i] = 0;
    __syncthreads();
    for (long long i = (long long)blockIdx.x * 256 + threadIdx.x; i < E;
         i += (long long)gridDim.x * 256)
        atomicAdd(&h[ei[E + i] >> 7], 1);
    __syncthreads();
    for (int i = threadIdx.x; i < NB; i += 256) {
        int v = h[i];
        if (v) atomicAdd(&bcnt[i], v);
    }
}

// single-block exclusive scan of bucket counts -> bases (and bcur seed)
__global__ void k_bscan(const int* __restrict__ bcnt, int NB, int E,
                        int* __restrict__ bases, int* __restrict__ bcur) {
    __shared__ int s[1024];
    int tid = threadIdx.x;
    int v = (tid < NB) ? bcnt[tid] : 0;
    s[tid] = v;
    __syncthreads();
    for (int off = 1; off < 1024; off <<= 1) {
        int t = (tid >= off) ? s[tid - off] : 0;
        __syncthreads();
        s[tid] += t;
        __syncthreads();
    }
    if (tid < NB) {
        int ex = s[tid] - v;
        bases[tid] = ex;
        bcur[tid] = ex;
        if (tid == NB - 1) bases[NB] = E;
    }
}

// partition edges into dst-buckets; output packed (dst_local<<17 | src), bucket-contiguous
__global__ __launch_bounds__(256) void k_part(const int* __restrict__ ei, int E, int NB,
                                              int* __restrict__ bcur, int* __restrict__ pp) {
    __shared__ int hist[1024], lbase[1024], gbase[1024], lcur[1024];
    __shared__ int stage[TILE], tgt[TILE];
    int* part = gbase;  // alias: gbase unused until after scan
    int tid = threadIdx.x;
    long long t0 = (long long)blockIdx.x * TILE;
    int nE = (int)(((long long)E - t0 < TILE) ? ((long long)E - t0) : TILE);

    for (int b = tid; b < NB; b += 256) hist[b] = 0;
    __syncthreads();
    for (int i = tid; i < nE; i += 256) {
        int d = ei[E + t0 + i];
        atomicAdd(&hist[d >> 7], 1);
    }
    __syncthreads();
    // exclusive scan hist -> lbase (NB <= 1024), 4 buckets per thread
    int i0 = tid * 4;
    int c0 = (i0 + 0 < NB) ? hist[i0 + 0] : 0;
    int c1 = (i0 + 1 < NB) ? hist[i0 + 1] : 0;
    int c2 = (i0 + 2 < NB) ? hist[i0 + 2] : 0;
    int c3 = (i0 + 3 < NB) ? hist[i0 + 3] : 0;
    int sum = c0 + c1 + c2 + c3;
    part[tid] = sum;
    __syncthreads();
    for (int off = 1; off < 256; off <<= 1) {
        int t = (tid >= off) ? part[tid - off] : 0;
        __syncthreads();
        part[tid] += t;
        __syncthreads();
    }
    int ex = part[tid] - sum;
    if (i0 + 0 < NB) { lbase[i0 + 0] = ex; ex += c0; }
    if (i0 + 1 < NB) { lbase[i0 + 1] = ex; ex += c1; }
    if (i0 + 2 < NB) { lbase[i0 + 2] = ex; ex += c2; }
    if (i0 + 3 < NB) { lbase[i0 + 3] = ex; ex += c3; }
    __syncthreads();  // part (=gbase) consumed; safe to overwrite
    for (int b = tid; b < NB; b += 256) {
        int h = hist[b];
        gbase[b] = h ? atomicAdd(&bcur[b], h) : 0;
        lcur[b] = 0;
    }
    __syncthreads();
    for (int i = tid; i < nE; i += 256) {
        int s = ei[t0 + i];
        int d = ei[E + t0 + i];
        int b = d >> 7;
        int lo = atomicAdd(&lcur[b], 1);
        int slot = lbase[b] + lo;
        stage[slot] = ((d - (b << 7)) << 17) | s;
        tgt[slot] = gbase[b] + lo;
    }
    __syncthreads();
    for (int i = tid; i < nE; i += 256)
        pp[tgt[i]] = stage[i];
}

// per-bucket: count node degrees from pp, scan -> rowptr/dinv, then scatter col
__global__ __launch_bounds__(256) void k_csr(const int* __restrict__ pp,
                                             const int* __restrict__ bases,
                                             int N, int E,
                                             int* __restrict__ rowptr,
                                             float* __restrict__ dinv,
                                             int* __restrict__ col) {
    __shared__ int lc[BSZ], rp[BSZ], sc[BSZ];
    int b = blockIdx.x, tid = threadIdx.x;
    int n0 = b << 7;
    int base = bases[b];
    int cnt = bases[b + 1] - base;
    if (tid < BSZ) lc[tid] = 0;
    __syncthreads();
    for (int i = tid; i < cnt; i += 256)
        atomicAdd(&lc[pp[base + i] >> 17], 1);
    __syncthreads();
    if (tid < BSZ) sc[tid] = lc[tid];
    __syncthreads();
    for (int off = 1; off < BSZ; off <<= 1) {
        int t = (tid < BSZ && tid >= off) ? sc[tid - off] : 0;
        __syncthreads();
        if (tid < BSZ) sc[tid] += t;
        __syncthreads();
    }
    if (tid < BSZ) {
        int node = n0 + tid;
        int ex = base + sc[tid] - lc[tid];  // exclusive prefix
        rp[tid] = ex;
        if (node < N) {
            rowptr[node] = ex;
            dinv[node] = rsqrtf((float)(lc[tid] + 1));  // +1 self-loop
            if (node == N - 1) rowptr[N] = E;
        }
        lc[tid] = 0;
    }
    __syncthreads();
    for (int i = tid; i < cnt; i += 256) {
        int v = pp[base + i];
        int dl = v >> 17;
        int lo = atomicAdd(&lc[dl], 1);
        col[rp[dl] + lo] = v & 0x1FFFF;
    }
}

// h1s[n][k] = dinv[n] * sum_j x[n][j] * W1[j][k]   (pre-scaled by dinv)
// 64 nodes/block, 4 waves; wave q computes k-octet [8q,8q+8) for all 64 nodes.
// 5 float4 x-loads batched into named regs per chunk -> 5 outstanding loads/lane.
__global__ __launch_bounds__(256) void k_gemm1(const float* __restrict__ x,
                                               const float* __restrict__ W1,
                                               const float* __restrict__ dinv,
                                               float* __restrict__ h1s, int n) {
    int lane = threadIdx.x & 63;
    int q = __builtin_amdgcn_readfirstlane(threadIdx.x >> 6);  // k-octet index
    int node = blockIdx.x * 64 + lane;
    bool valid = node < n;
    const float4* xr = reinterpret_cast<const float4*>(
        x + (size_t)(valid ? node : (n - 1)) * NFEAT);
    const float* Wq = W1 + q * 8;
    float acc[8];
#pragma unroll
    for (int i = 0; i < 8; ++i) acc[i] = 0.f;

    auto fma4 = [&](const float4& xv, int c) {
        const float* w0 = Wq + (size_t)(4 * c + 0) * HID;
        const float* w1 = Wq + (size_t)(4 * c + 1) * HID;
        const float* w2 = Wq + (size_t)(4 * c + 2) * HID;
        const float* w3 = Wq + (size_t)(4 * c + 3) * HID;
#pragma unroll
        for (int i = 0; i < 8; ++i) {
            acc[i] = fmaf(xv.x, w0[i], acc[i]);
            acc[i] = fmaf(xv.y, w1[i], acc[i]);
            acc[i] = fmaf(xv.z, w2[i], acc[i]);
            acc[i] = fmaf(xv.w, w3[i], acc[i]);
        }
    };

#pragma unroll 3
    for (int cc = 0; cc < 15; ++cc) {  // 75 float4 = 15 chunks of 5
        int c = 5 * cc;
        float4 v0 = xr[c + 0];
        float4 v1 = xr[c + 1];
        float4 v2 = xr[c + 2];
        float4 v3 = xr[c + 3];
        float4 v4 = xr[c + 4];
        fma4(v0, c + 0);
        fma4(v1, c + 1);
        fma4(v2, c + 2);
        fma4(v3, c + 3);
        fma4(v4, c + 4);
    }
    if (valid) {
        float dd = dinv[node];
        float4* dst = reinterpret_cast<float4*>(h1s + (size_t)node * HID + q * 8);
        dst[0] = make_float4(dd * acc[0], dd * acc[1], dd * acc[2], dd * acc[3]);
        dst[1] = make_float4(dd * acc[4], dd * acc[5], dd * acc[6], dd * acc[7]);
    }
}

// CSR gather aggregate layer 1 (pre-scaled h1s), fused bias + tanh.
// 8 lanes/node x float4; 4-edge unroll (32 gathers in flight/wave).
__global__ __launch_bounds__(256) void k_agg1(const float* __restrict__ h1s,
                                              const int* __restrict__ rowptr,
                                              const int* __restrict__ col,
                                              const float* __restrict__ dinv,
                                              const float* __restrict__ b1,
                                              float* __restrict__ h2, int n) {
    int node = blockIdx.x * 32 + (threadIdx.x >> 3);
    int l = threadIdx.x & 7;  // float4 lane within node
    if (node >= n) return;
    const float4* h4 = reinterpret_cast<const float4*>(h1s);
    int beg = rowptr[node], end = rowptr[node + 1];
    float4 a0 = h4[(size_t)node * 8 + l];  // self-loop term (pre-scaled)
    float4 a1 = make_float4(0.f, 0.f, 0.f, 0.f);
    float4 a2 = make_float4(0.f, 0.f, 0.f, 0.f);
    float4 a3 = make_float4(0.f, 0.f, 0.f, 0.f);
    int j = beg;
    for (; j + 3 < end; j += 4) {
        int s0 = col[j], s1 = col[j + 1], s2 = col[j + 2], s3 = col[j + 3];
        float4 v0 = h4[(size_t)s0 * 8 + l];
        float4 v1 = h4[(size_t)s1 * 8 + l];
        float4 v2 = h4[(size_t)s2 * 8 + l];
        float4 v3 = h4[(size_t)s3 * 8 + l];
        a0.x += v0.x; a0.y += v0.y; a0.z += v0.z; a0.w += v0.w;
        a1.x += v1.x; a1.y += v1.y; a1.z += v1.z; a1.w += v1.w;
        a2.x += v2.x; a2.y += v2.y; a2.z += v2.z; a2.w += v2.w;
        a3.x += v3.x; a3.y += v3.y; a3.z += v3.z; a3.w += v3.w;
    }
    for (; j < end; ++j) {
        float4 v = h4[(size_t)col[j] * 8 + l];
        a0.x += v.x; a0.y += v.y; a0.z += v.z; a0.w += v.w;
    }
    float dd = dinv[node];
    const float4* b4 = reinterpret_cast<const float4*>(b1);
    float4 bv = b4[l];
    float4 r;
    r.x = tanhf(fmaf(dd, (a0.x + a1.x) + (a2.x + a3.x), bv.x));
    r.y = tanhf(fmaf(dd, (a0.y + a1.y) + (a2.y + a3.y), bv.y));
    r.z = tanhf(fmaf(dd, (a0.z + a1.z) + (a2.z + a3.z), bv.z));
    r.w = tanhf(fmaf(dd, (a0.w + a1.w) + (a2.w + a3.w), bv.w));
    reinterpret_cast<float4*>(h2)[(size_t)node * 8 + l] = r;
}

// gs[n][c] = dinv[n] * sum_k h2[n][k] * W2[k][c], padded row stride GP=16
__global__ __launch_bounds__(256) void k_gemm2(const float* __restrict__ h2,
                                               const float* __restrict__ W2,
                                               const float* __restrict__ dinv,
                                               float* __restrict__ gs, int n) {
    __shared__ float Ws[HID * NCLS];
    for (int i = threadIdx.x; i < HID * NCLS; i += 256) Ws[i] = W2[i];
    __syncthreads();
    int t = blockIdx.x * 256 + threadIdx.x;
    int node = t >> 4, c = t & 15;
    if (node >= n || c >= NCLS) return;
    const float* hr = h2 + (size_t)node * HID;
    float acc = 0.f;
#pragma unroll
    for (int k = 0; k < HID; ++k) acc = fmaf(hr[k], Ws[k * NCLS + c], acc);
    gs[(size_t)node * GP + c] = acc * dinv[node];
}

// CSR gather aggregate layer 2 (pre-scaled gs), fused bias + log-softmax.
// 4 lanes/node x float4 (one gs row = 4 float4s); 2-edge unroll.
__global__ __launch_bounds__(256) void k_agg2(const float* __restrict__ gs,
                                              const int* __restrict__ rowptr,
                                              const int* __restrict__ col,
                                              const float* __restrict__ dinv,
                                              const float* __restrict__ b2,
                                              float* __restrict__ out, int n) {
    int node = blockIdx.x * 64 + (threadIdx.x >> 2);
    int l = threadIdx.x & 3;  // float4 lane: classes 4l..4l+3
    if (node >= n) return;
    const float4* g4 = reinterpret_cast<const float4*>(gs);
    int beg = rowptr[node], end = rowptr[node + 1];
    float4 a0 = g4[(size_t)node * 4 + l];  // self-loop term (pre-scaled)
    float4 a1 = make_float4(0.f, 0.f, 0.f, 0.f);
    int j = beg;
    for (; j + 1 < end; j += 2) {
        int s0 = col[j], s1 = col[j + 1];
        float4 v0 = g4[(size_t)s0 * 4 + l];
        float4 v1 = g4[(size_t)s1 * 4 + l];
        a0.x += v0.x; a0.y += v0.y; a0.z += v0.z; a0.w += v0.w;
        a1.x += v1.x; a1.y += v1.y; a1.z += v1.z; a1.w += v1.w;
    }
    if (j < end) {
        float4 v = g4[(size_t)col[j] * 4 + l];
        a0.x += v.x; a0.y += v.y; a0.z += v.z; a0.w += v.w;
    }
    float dd = dinv[node];
    int c0 = 4 * l;
    float val[4];
    float av[4] = {a0.x + a1.x, a0.y + a1.y, a0.z + a1.z, a0.w + a1.w};
#pragma unroll
    for (int i = 0; i < 4; ++i) {
        int c = c0 + i;
        val[i] = (c < NCLS) ? fmaf(dd, av[i], b2[c]) : -FLT_MAX;
    }
    float m = fmaxf(fmaxf(val[0], val[1]), fmaxf(val[2], val[3]));
    m = fmaxf(m, __shfl_xor(m, 1, 4));
    m = fmaxf(m, __shfl_xor(m, 2, 4));
    float s = 0.f;
#pragma unroll
    for (int i = 0; i < 4; ++i)
        if (c0 + i < NCLS) s += expf(val[i] - m);
    s += __shfl_xor(s, 1, 4);
    s += __shfl_xor(s, 2, 4);
    float ls = m + logf(s);
    float* orow = out + (size_t)node * NCLS;
#pragma unroll
    for (int i = 0; i < 4; ++i)
        if (c0 + i < NCLS) orow[c0 + i] = val[i] - ls;
}

static inline size_t align256(size_t b) { return (b + 255) & ~(size_t)255; }

extern "C" void kernel_launch(void* const* d_in, const int* in_sizes, int n_in,
                              void* d_out, int out_size, void* d_ws, size_t ws_size,
                              hipStream_t stream) {
    const float* x  = (const float*)d_in[0];
    const int*   ei = (const int*)d_in[1];
    const float* W1 = (const float*)d_in[2];
    const float* b1 = (const float*)d_in[3];
    const float* W2 = (const float*)d_in[4];
    const float* b2 = (const float*)d_in[5];
    float* out = (float*)d_out;

    const int N = in_sizes[0] / NFEAT;   // 100000
    const int E = in_sizes[1] / 2;       // 3200000
    const int NB = (N + BSZ - 1) / BSZ;  // 782 dst-buckets

    char* p = (char*)d_ws;
    int* bcnt   = (int*)p;  p += align256(1024 * 4);
    int* bases  = (int*)p;  p += align256(1025 * 4);
    int* bcur   = (int*)p;  p += align256(1024 * 4);
    int* rowptr = (int*)p;  p += align256((size_t)(N + 1) * 4);
    int* pp     = (int*)p;  p += align256((size_t)E * 4);   // packed bucketed edges
    int* col    = (int*)p;  p += align256((size_t)E * 4);
    float* dinv = (float*)p; p += align256((size_t)N * 4);
    float* h1s  = (float*)p; p += align256((size_t)N * HID * 4);
    float* h2   = (float*)p; p += align256((size_t)N * HID * 4);
    float* gs   = h1s;  // N*GP floats; h1s dead after k_agg1

    dim3 B(256);
    int nT = (E + TILE - 1) / TILE;

    k_zero_i<<<4, B, 0, stream>>>(bcnt, 1024);
    k_bhist<<<128, B, 0, stream>>>(ei, E, NB, bcnt);
    k_bscan<<<1, 1024, 0, stream>>>(bcnt, NB, E, bases, bcur);
    k_part<<<nT, B, 0, stream>>>(ei, E, NB, bcur, pp);
    k_csr<<<NB, B, 0, stream>>>(pp, bases, N, E, rowptr, dinv, col);

    k_gemm1<<<(N + 63) / 64, B, 0, stream>>>(x, W1, dinv, h1s, N);
    k_agg1<<<(N + 31) / 32, B, 0, stream>>>(h1s, rowptr, col, dinv, b1, h2, N);
    k_gemm2<<<(N * 16 + 255) / 256, B, 0, stream>>>(h2, W2, dinv, gs, N);
    k_agg2<<<(N + 63) / 64, B, 0, stream>>>(gs, rowptr, col, dinv, b2, out, N);
}

// Round 12
// 261.583 us; speedup vs baseline: 1.0052x; 1.0052x over previous
//
#include <hip/hip_runtime.h>
#include <math.h>
#include <float.h>

#define NFEAT 300
#define HID 32
#define NCLS 10
#define GP 16     // padded row stride for layer-2 logits
#define BSZ 128   // nodes per dst-bucket (bucket = dst >> 7)
#define TILE 8192 // edges per k_part tile

__global__ void k_zero_i(int* __restrict__ p, int n) {
    int i = blockIdx.x * 256 + threadIdx.x;
    if (i < n) p[i] = 0;
}

// bucket-level histogram: LDS-privatized, merged via global atomics (782 counters)
__global__ __launch_bounds__(256) void k_bhist(const int* __restrict__ ei, int E, int NB,
                                               int* __restrict__ bcnt) {
    __shared__ int h[1024];
    for (int i = threadIdx.x; i < NB; i += 256) h[i] = 0;
    __syncthreads();
    for (long long i = (long long)blockIdx.x * 256 + threadIdx.x; i < E;
         i += (long long)gridDim.x * 256)
        atomicAdd(&h[ei[E + i] >> 7], 1);
    __syncthreads();
    for (int i = threadIdx.x; i < NB; i += 256) {
        int v = h[i];
        if (v) atomicAdd(&bcnt[i], v);
    }
}

// single-block exclusive scan of bucket counts -> bases (and bcur seed)
__global__ void k_bscan(const int* __restrict__ bcnt, int NB, int E,
                        int* __restrict__ bases, int* __restrict__ bcur) {
    __shared__ int s[1024];
    int tid = threadIdx.x;
    int v = (tid < NB) ? bcnt[tid] : 0;
    s[tid] = v;
    __syncthreads();
    for (int off = 1; off < 1024; off <<= 1) {
        int t = (tid >= off) ? s[tid - off] : 0;
        __syncthreads();
        s[tid] += t;
        __syncthreads();
    }
    if (tid < NB) {
        int ex = s[tid] - v;
        bases[tid] = ex;
        bcur[tid] = ex;
        if (tid == NB - 1) bases[NB] = E;
    }
}

// partition edges into dst-buckets; output packed (dst_local<<17 | src), bucket-contiguous
__global__ __launch_bounds__(256) void k_part(const int* __restrict__ ei, int E, int NB,
                                              int* __restrict__ bcur, int* __restrict__ pp) {
    __shared__ int hist[1024], lbase[1024], gbase[1024], lcur[1024];
    __shared__ int stage[TILE], tgt[TILE];
    int* part = gbase;  // alias: gbase unused until after scan
    int tid = threadIdx.x;
    long long t0 = (long long)blockIdx.x * TILE;
    int nE = (int)(((long long)E - t0 < TILE) ? ((long long)E - t0) : TILE);

    for (int b = tid; b < NB; b += 256) hist[b] = 0;
    __syncthreads();
    for (int i = tid; i < nE; i += 256) {
        int d = ei[E + t0 + i];
        atomicAdd(&hist[d >> 7], 1);
    }
    __syncthreads();
    // exclusive scan hist -> lbase (NB <= 1024), 4 buckets per thread
    int i0 = tid * 4;
    int c0 = (i0 + 0 < NB) ? hist[i0 + 0] : 0;
    int c1 = (i0 + 1 < NB) ? hist[i0 + 1] : 0;
    int c2 = (i0 + 2 < NB) ? hist[i0 + 2] : 0;
    int c3 = (i0 + 3 < NB) ? hist[i0 + 3] : 0;
    int sum = c0 + c1 + c2 + c3;
    part[tid] = sum;
    __syncthreads();
    for (int off = 1; off < 256; off <<= 1) {
        int t = (tid >= off) ? part[tid - off] : 0;
        __syncthreads();
        part[tid] += t;
        __syncthreads();
    }
    int ex = part[tid] - sum;
    if (i0 + 0 < NB) { lbase[i0 + 0] = ex; ex += c0; }
    if (i0 + 1 < NB) { lbase[i0 + 1] = ex; ex += c1; }
    if (i0 + 2 < NB) { lbase[i0 + 2] = ex; ex += c2; }
    if (i0 + 3 < NB) { lbase[i0 + 3] = ex; ex += c3; }
    __syncthreads();  // part (=gbase) consumed; safe to overwrite
    for (int b = tid; b < NB; b += 256) {
        int h = hist[b];
        gbase[b] = h ? atomicAdd(&bcur[b], h) : 0;
        lcur[b] = 0;
    }
    __syncthreads();
    for (int i = tid; i < nE; i += 256) {
        int s = ei[t0 + i];
        int d = ei[E + t0 + i];
        int b = d >> 7;
        int lo = atomicAdd(&lcur[b], 1);
        int slot = lbase[b] + lo;
        stage[slot] = ((d - (b << 7)) << 17) | s;
        tgt[slot] = gbase[b] + lo;
    }
    __syncthreads();
    for (int i = tid; i < nE; i += 256)
        pp[tgt[i]] = stage[i];
}

// per-bucket: count node degrees from pp, scan -> rowptr/dinv, then scatter col
__global__ __launch_bounds__(256) void k_csr(const int* __restrict__ pp,
                                             const int* __restrict__ bases,
                                             int N, int E,
                                             int* __restrict__ rowptr,
                                             float* __restrict__ dinv,
                                             int* __restrict__ col) {
    __shared__ int lc[BSZ], rp[BSZ], sc[BSZ];
    int b = blockIdx.x, tid = threadIdx.x;
    int n0 = b << 7;
    int base = bases[b];
    int cnt = bases[b + 1] - base;
    if (tid < BSZ) lc[tid] = 0;
    __syncthreads();
    for (int i = tid; i < cnt; i += 256)
        atomicAdd(&lc[pp[base + i] >> 17], 1);
    __syncthreads();
    if (tid < BSZ) sc[tid] = lc[tid];
    __syncthreads();
    for (int off = 1; off < BSZ; off <<= 1) {
        int t = (tid < BSZ && tid >= off) ? sc[tid - off] : 0;
        __syncthreads();
        if (tid < BSZ) sc[tid] += t;
        __syncthreads();
    }
    if (tid < BSZ) {
        int node = n0 + tid;
        int ex = base + sc[tid] - lc[tid];  // exclusive prefix
        rp[tid] = ex;
        if (node < N) {
            rowptr[node] = ex;
            dinv[node] = rsqrtf((float)(lc[tid] + 1));  // +1 self-loop
            if (node == N - 1) rowptr[N] = E;
        }
        lc[tid] = 0;
    }
    __syncthreads();
    for (int i = tid; i < cnt; i += 256) {
        int v = pp[base + i];
        int dl = v >> 17;
        int lo = atomicAdd(&lc[dl], 1);
        col[rp[dl] + lo] = v & 0x1FFFF;
    }
}

// h1s[n][k] = dinv[n] * sum_j x[n][j] * W1[j][k]   (pre-scaled by dinv)
// 64 nodes/block, 4 waves; wave q computes k-octet [8q,8q+8) for all 64 nodes.
// x staged through LDS with COALESCED global reads (each line fetched once),
// double-buffered, conflict-free padded-stride-61 LDS reads. W via s_load.
__global__ __launch_bounds__(256) void k_gemm1(const float* __restrict__ x,
                                               const float* __restrict__ W1,
                                               const float* __restrict__ dinv,
                                               float* __restrict__ h1s, int n) {
    __shared__ float xs[2][64 * 61];  // 5 chunks of 60 feats, stride 61
    int tid = threadIdx.x;
    int lane = tid & 63;
    int q = __builtin_amdgcn_readfirstlane(tid >> 6);  // k-octet index
    int n0 = blockIdx.x * 64;
    int node = n0 + lane;
    const float4* x4 = reinterpret_cast<const float4*>(x);

    float acc[8];
#pragma unroll
    for (int i = 0; i < 8; ++i) acc[i] = 0.f;

    // stage chunk 0: 64 rows x 15 float4, row-sequential (coalesced)
    for (int i = tid; i < 960; i += 256) {
        int r = i / 15, f = i % 15;
        int gr = min(n0 + r, n - 1);
        float4 v = x4[(size_t)gr * 75 + f];
        float* d = &xs[0][r * 61 + f * 4];
        d[0] = v.x; d[1] = v.y; d[2] = v.z; d[3] = v.w;
    }
    __syncthreads();

    int cur = 0;
    for (int ch = 0; ch < 5; ++ch) {
        // issue next chunk's global loads into regs (overlap with compute)
        float4 v0, v1, v2, v3;
        int i0 = tid, i1 = tid + 256, i2 = tid + 512, i3 = tid + 768;
        bool more = (ch + 1 < 5);
        if (more) {
            int cb = (ch + 1) * 15;
            { int r = i0 / 15, f = i0 % 15; v0 = x4[(size_t)min(n0 + r, n - 1) * 75 + cb + f]; }
            { int r = i1 / 15, f = i1 % 15; v1 = x4[(size_t)min(n0 + r, n - 1) * 75 + cb + f]; }
            { int r = i2 / 15, f = i2 % 15; v2 = x4[(size_t)min(n0 + r, n - 1) * 75 + cb + f]; }
            if (i3 < 960) { int r = i3 / 15, f = i3 % 15; v3 = x4[(size_t)min(n0 + r, n - 1) * 75 + cb + f]; }
        }
        // compute current chunk: lane's own row from LDS, W octet from SGPRs
        const float* xrow = &xs[cur][lane * 61];
        const float* wbase = W1 + (size_t)(ch * 60) * HID + q * 8;
#pragma unroll 6
        for (int j = 0; j < 60; ++j) {
            float xv = xrow[j];
            const float* w = wbase + (size_t)j * HID;
#pragma unroll
            for (int i = 0; i < 8; ++i) acc[i] = fmaf(xv, w[i], acc[i]);
        }
        // write staged regs into the other buffer
        if (more) {
            float* xb = xs[cur ^ 1];
            { int r = i0 / 15, f = i0 % 15; float* d = &xb[r * 61 + f * 4];
              d[0] = v0.x; d[1] = v0.y; d[2] = v0.z; d[3] = v0.w; }
            { int r = i1 / 15, f = i1 % 15; float* d = &xb[r * 61 + f * 4];
              d[0] = v1.x; d[1] = v1.y; d[2] = v1.z; d[3] = v1.w; }
            { int r = i2 / 15, f = i2 % 15; float* d = &xb[r * 61 + f * 4];
              d[0] = v2.x; d[1] = v2.y; d[2] = v2.z; d[3] = v2.w; }
            if (i3 < 960) { int r = i3 / 15, f = i3 % 15; float* d = &xb[r * 61 + f * 4];
              d[0] = v3.x; d[1] = v3.y; d[2] = v3.z; d[3] = v3.w; }
        }
        __syncthreads();
        cur ^= 1;
    }
    if (node < n) {
        float dd = dinv[node];
        float4* dst = reinterpret_cast<float4*>(h1s + (size_t)node * HID + q * 8);
        dst[0] = make_float4(dd * acc[0], dd * acc[1], dd * acc[2], dd * acc[3]);
        dst[1] = make_float4(dd * acc[4], dd * acc[5], dd * acc[6], dd * acc[7]);
    }
}

// CSR gather aggregate layer 1 (pre-scaled h1s), fused bias + tanh.
// 8 lanes/node x float4; 4-edge unroll (32 gathers in flight/wave).
__global__ __launch_bounds__(256) void k_agg1(const float* __restrict__ h1s,
                                              const int* __restrict__ rowptr,
                                              const int* __restrict__ col,
                                              const float* __restrict__ dinv,
                                              const float* __restrict__ b1,
                                              float* __restrict__ h2, int n) {
    int node = blockIdx.x * 32 + (threadIdx.x >> 3);
    int l = threadIdx.x & 7;  // float4 lane within node
    if (node >= n) return;
    const float4* h4 = reinterpret_cast<const float4*>(h1s);
    int beg = rowptr[node], end = rowptr[node + 1];
    float4 a0 = h4[(size_t)node * 8 + l];  // self-loop term (pre-scaled)
    float4 a1 = make_float4(0.f, 0.f, 0.f, 0.f);
    float4 a2 = make_float4(0.f, 0.f, 0.f, 0.f);
    float4 a3 = make_float4(0.f, 0.f, 0.f, 0.f);
    int j = beg;
    for (; j + 3 < end; j += 4) {
        int s0 = col[j], s1 = col[j + 1], s2 = col[j + 2], s3 = col[j + 3];
        float4 v0 = h4[(size_t)s0 * 8 + l];
        float4 v1 = h4[(size_t)s1 * 8 + l];
        float4 v2 = h4[(size_t)s2 * 8 + l];
        float4 v3 = h4[(size_t)s3 * 8 + l];
        a0.x += v0.x; a0.y += v0.y; a0.z += v0.z; a0.w += v0.w;
        a1.x += v1.x; a1.y += v1.y; a1.z += v1.z; a1.w += v1.w;
        a2.x += v2.x; a2.y += v2.y; a2.z += v2.z; a2.w += v2.w;
        a3.x += v3.x; a3.y += v3.y; a3.z += v3.z; a3.w += v3.w;
    }
    for (; j < end; ++j) {
        float4 v = h4[(size_t)col[j] * 8 + l];
        a0.x += v.x; a0.y += v.y; a0.z += v.z; a0.w += v.w;
    }
    float dd = dinv[node];
    const float4* b4 = reinterpret_cast<const float4*>(b1);
    float4 bv = b4[l];
    float4 r;
    r.x = tanhf(fmaf(dd, (a0.x + a1.x) + (a2.x + a3.x), bv.x));
    r.y = tanhf(fmaf(dd, (a0.y + a1.y) + (a2.y + a3.y), bv.y));
    r.z = tanhf(fmaf(dd, (a0.z + a1.z) + (a2.z + a3.z), bv.z));
    r.w = tanhf(fmaf(dd, (a0.w + a1.w) + (a2.w + a3.w), bv.w));
    reinterpret_cast<float4*>(h2)[(size_t)node * 8 + l] = r;
}

// gs[n][c] = dinv[n] * sum_k h2[n][k] * W2[k][c], padded row stride GP=16
__global__ __launch_bounds__(256) void k_gemm2(const float* __restrict__ h2,
                                               const float* __restrict__ W2,
                                               const float* __restrict__ dinv,
                                               float* __restrict__ gs, int n) {
    __shared__ float Ws[HID * NCLS];
    for (int i = threadIdx.x; i < HID * NCLS; i += 256) Ws[i] = W2[i];
    __syncthreads();
    int t = blockIdx.x * 256 + threadIdx.x;
    int node = t >> 4, c = t & 15;
    if (node >= n || c >= NCLS) return;
    const float* hr = h2 + (size_t)node * HID;
    float acc = 0.f;
#pragma unroll
    for (int k = 0; k < HID; ++k) acc = fmaf(hr[k], Ws[k * NCLS + c], acc);
    gs[(size_t)node * GP + c] = acc * dinv[node];
}

// CSR gather aggregate layer 2 (pre-scaled gs), fused bias + log-softmax.
// 4 lanes/node x float4 (one gs row = 4 float4s); 2-edge unroll.
__global__ __launch_bounds__(256) void k_agg2(const float* __restrict__ gs,
                                              const int* __restrict__ rowptr,
                                              const int* __restrict__ col,
                                              const float* __restrict__ dinv,
                                              const float* __restrict__ b2,
                                              float* __restrict__ out, int n) {
    int node = blockIdx.x * 64 + (threadIdx.x >> 2);
    int l = threadIdx.x & 3;  // float4 lane: classes 4l..4l+3
    if (node >= n) return;
    const float4* g4 = reinterpret_cast<const float4*>(gs);
    int beg = rowptr[node], end = rowptr[node + 1];
    float4 a0 = g4[(size_t)node * 4 + l];  // self-loop term (pre-scaled)
    float4 a1 = make_float4(0.f, 0.f, 0.f, 0.f);
    int j = beg;
    for (; j + 1 < end; j += 2) {
        int s0 = col[j], s1 = col[j + 1];
        float4 v0 = g4[(size_t)s0 * 4 + l];
        float4 v1 = g4[(size_t)s1 * 4 + l];
        a0.x += v0.x; a0.y += v0.y; a0.z += v0.z; a0.w += v0.w;
        a1.x += v1.x; a1.y += v1.y; a1.z += v1.z; a1.w += v1.w;
    }
    if (j < end) {
        float4 v = g4[(size_t)col[j] * 4 + l];
        a0.x += v.x; a0.y += v.y; a0.z += v.z; a0.w += v.w;
    }
    float dd = dinv[node];
    int c0 = 4 * l;
    float val[4];
    float av[4] = {a0.x + a1.x, a0.y + a1.y, a0.z + a1.z, a0.w + a1.w};
#pragma unroll
    for (int i = 0; i < 4; ++i) {
        int c = c0 + i;
        val[i] = (c < NCLS) ? fmaf(dd, av[i], b2[c]) : -FLT_MAX;
    }
    float m = fmaxf(fmaxf(val[0], val[1]), fmaxf(val[2], val[3]));
    m = fmaxf(m, __shfl_xor(m, 1, 4));
    m = fmaxf(m, __shfl_xor(m, 2, 4));
    float s = 0.f;
#pragma unroll
    for (int i = 0; i < 4; ++i)
        if (c0 + i < NCLS) s += expf(val[i] - m);
    s += __shfl_xor(s, 1, 4);
    s += __shfl_xor(s, 2, 4);
    float ls = m + logf(s);
    float* orow = out + (size_t)node * NCLS;
#pragma unroll
    for (int i = 0; i < 4; ++i)
        if (c0 + i < NCLS) orow[c0 + i] = val[i] - ls;
}

static inline size_t align256(size_t b) { return (b + 255) & ~(size_t)255; }

extern "C" void kernel_launch(void* const* d_in, const int* in_sizes, int n_in,
                              void* d_out, int out_size, void* d_ws, size_t ws_size,
                              hipStream_t stream) {
    const float* x  = (const float*)d_in[0];
    const int*   ei = (const int*)d_in[1];
    const float* W1 = (const float*)d_in[2];
    const float* b1 = (const float*)d_in[3];
    const float* W2 = (const float*)d_in[4];
    const float* b2 = (const float*)d_in[5];
    float* out = (float*)d_out;

    const int N = in_sizes[0] / NFEAT;   // 100000
    const int E = in_sizes[1] / 2;       // 3200000
    const int NB = (N + BSZ - 1) / BSZ;  // 782 dst-buckets

    char* p = (char*)d_ws;
    int* bcnt   = (int*)p;  p += align256(1024 * 4);
    int* bases  = (int*)p;  p += align256(1025 * 4);
    int* bcur   = (int*)p;  p += align256(1024 * 4);
    int* rowptr = (int*)p;  p += align256((size_t)(N + 1) * 4);
    int* pp     = (int*)p;  p += align256((size_t)E * 4);   // packed bucketed edges
    int* col    = (int*)p;  p += align256((size_t)E * 4);
    float* dinv = (float*)p; p += align256((size_t)N * 4);
    float* h1s  = (float*)p; p += align256((size_t)N * HID * 4);
    float* h2   = (float*)p; p += align256((size_t)N * HID * 4);
    float* gs   = h1s;  // N*GP floats; h1s dead after k_agg1

    dim3 B(256);
    int nT = (E + TILE - 1) / TILE;

    k_zero_i<<<4, B, 0, stream>>>(bcnt, 1024);
    k_bhist<<<128, B, 0, stream>>>(ei, E, NB, bcnt);
    k_bscan<<<1, 1024, 0, stream>>>(bcnt, NB, E, bases, bcur);
    k_part<<<nT, B, 0, stream>>>(ei, E, NB, bcur, pp);
    k_csr<<<NB, B, 0, stream>>>(pp, bases, N, E, rowptr, dinv, col);

    k_gemm1<<<(N + 63) / 64, B, 0, stream>>>(x, W1, dinv, h1s, N);
    k_agg1<<<(N + 31) / 32, B, 0, stream>>>(h1s, rowptr, col, dinv, b1, h2, N);
    k_gemm2<<<(N * 16 + 255) / 256, B, 0, stream>>>(h2, W2, dinv, gs, N);
    k_agg2<<<(N + 63) / 64, B, 0, stream>>>(gs, rowptr, col, dinv, b2, out, N);
}